// Round 3
// baseline (8156.163 us; speedup 1.0000x reference)
//
#include <hip/hip_runtime.h>

// SIR recurrence, steps=200000, output = trajectory [steps-1, 3] float32.
//
// R2 -> R3:
//  (a) Analytic early stop: S monotone non-increasing => f = 1+b*S-g only
//      decreases, so for f<1 future total change of each compartment is
//      bounded by rem = I/(1-f) (geometric tail with today's f, conservative).
//      Stop when rem*max(g, b*S) < 1e-4 (threshold is 4.5e-2 => 450x margin).
//      Cuts ~980 sequential steps to ~200-350.
//  (b) Packed stores: buffer 8 steps (24 floats) in regs, emit 6
//      global_store_dwordx4 per octet instead of 24 scalar dword stores.
//  (c) Fill kernel: one element per thread, coalesced.

struct FixInfo {
    int   t;        // first row index NOT written by the scan kernel
    float S, I, R;  // state to replicate into rows [t, n)
};

__global__ void sir_scan(const float* __restrict__ x,
                         const float* __restrict__ bw,
                         const float* __restrict__ gw,
                         float* __restrict__ out,
                         int n, FixInfo* __restrict__ fi) {
    if (threadIdx.x != 0) return;
    float S = x[0], I = x[1], R = x[2];
    float b = bw[0], g = gw[0];
    float cg = 1.0f - g;

    int t = 0;
    float* p = out;
    float vals[24];

    while (t + 8 <= n) {
        float pS = S, pI = I, pR = R;  // state before the octet's last step
#pragma unroll
        for (int k = 0; k < 8; ++k) {
            if (k == 7) { pS = S; pI = I; pR = R; }
            float f  = fmaf(b, S, cg);       // 1 + b*S - g
            float t1 = b * I;
            float nS = fmaf(-t1, S, S);      // S - b*S*I
            float nI = I * f;                // I*(1 + b*S - g)
            float nR = fmaf(g, I, R);        // R + g*I
            S = nS; I = nI; R = nR;
            vals[3 * k + 0] = S;
            vals[3 * k + 1] = I;
            vals[3 * k + 2] = R;
        }
        // 6 x 16B stores (96B per octet, base is 16B-aligned)
        float4* o4 = reinterpret_cast<float4*>(p);
#pragma unroll
        for (int j = 0; j < 6; ++j)
            o4[j] = reinterpret_cast<const float4*>(vals)[j];
        p += 24;
        t += 8;

        // exact bitwise fixpoint (fallback; step is a pure function of state)
        if (S == pS && I == pI && R == pR) break;

        // analytic early stop: bounded future change < 1e-4
        float f_next = fmaf(b, S, cg);
        if (f_next < 0.99999f) {
            float rem = I / (1.0f - f_next);        // >= sum of future I
            if (rem * fmaxf(g, b * S) < 1e-4f) break;
        }
    }

    // tail only if we ran all the way to n without stopping
    while (t < n) {
        float f  = fmaf(b, S, cg);
        float t1 = b * I;
        float nS = fmaf(-t1, S, S);
        float nI = I * f;
        float nR = fmaf(g, I, R);
        S = nS; I = nI; R = nR;
        p[0] = S; p[1] = I; p[2] = R;
        p += 3;
        ++t;
    }

    fi->t = t; fi->S = S; fi->I = I; fi->R = R;
}

// One float element per thread; rows >= t0 get the frozen state. Coalesced.
__global__ void sir_fill(float* __restrict__ out, int total,
                         const FixInfo* __restrict__ fi) {
    int j = blockIdx.x * blockDim.x + threadIdx.x;
    if (j >= total) return;
    int j0 = 3 * fi->t;
    if (j < j0) return;
    int c = j % 3;
    float v = (c == 0) ? fi->S : (c == 1) ? fi->I : fi->R;
    out[j] = v;
}

extern "C" void kernel_launch(void* const* d_in, const int* in_sizes, int n_in,
                              void* d_out, int out_size, void* d_ws, size_t ws_size,
                              hipStream_t stream) {
    const float* x  = (const float*)d_in[0];
    const float* bw = (const float*)d_in[1];
    const float* gw = (const float*)d_in[2];
    float* out = (float*)d_out;
    int n = out_size / 3;  // steps - 1 rows

    FixInfo* fi = (FixInfo*)d_ws;

    sir_scan<<<1, 64, 0, stream>>>(x, bw, gw, out, n, fi);

    int blocks = (out_size + 255) / 256;
    sir_fill<<<blocks, 256, 0, stream>>>(out, out_size, fi);
}

// Round 4
// 66.352 us; speedup vs baseline: 122.9220x; 122.9220x over previous
//
#include <hip/hip_runtime.h>

// SIR recurrence, steps=200000, output = trajectory [steps-1, 3] float32.
//
// R3 -> R4: revert to R2's proven scan structure verbatim (scalar stores, no
// register buffering / type punning -- R3's reinterpret_cast octet buffer was
// UB and miscompiled: scan ran all 200k steps at 101 cyc/step with vals[]
// spilled to scratch). Single delta vs R2: analytic early stop.
//   S monotone non-increasing => f = 1+b*S-g only decreases, so for f<1 the
//   total future change of each compartment is bounded by rem = I/(1-f)
//   (geometric tail with the current f, conservative). Stop when
//   rem*max(g, b*S) < 1e-4  (pass threshold 4.5e-2 => 450x margin).
// Bitwise one-step fixpoint check stays as backstop; honest tail loop keeps
// full correctness if neither fires.

struct FixInfo {
    int   t;        // first row index NOT written by the scan kernel
    float S, I, R;  // state to replicate into rows [t, n)
};

__global__ void sir_scan(const float* __restrict__ x,
                         const float* __restrict__ bw,
                         const float* __restrict__ gw,
                         float* __restrict__ out,
                         int n, FixInfo* __restrict__ fi) {
    if (threadIdx.x != 0) return;
    float S = x[0], I = x[1], R = x[2];
    float b = bw[0], g = gw[0];
    float cg = 1.0f - g;

    int t = 0;
    bool fixed = false;
    float* p = out;

    // main loop: octets of 8 steps, checks once per octet
    while (t + 8 <= n) {
        float pS = S, pI = I, pR = R;  // state one step before octet end
#pragma unroll
        for (int k = 0; k < 8; ++k) {
            pS = S; pI = I; pR = R;
            float f  = fmaf(b, S, cg);       // 1 + b*S - g
            float t1 = b * I;
            float nS = fmaf(-t1, S, S);      // S - b*S*I
            float nI = I * f;                // I*(1 + b*S - g)
            float nR = fmaf(g, I, R);        // R + g*I
            S = nS; I = nI; R = nR;
            p[0] = S; p[1] = I; p[2] = R;
            p += 3;
        }
        t += 8;

        // backstop: exact bitwise one-step fixpoint
        if (S == pS && I == pI && R == pR) { fixed = true; break; }

        // analytic early stop: bounded total future change < 1e-4
        float f_next = fmaf(b, S, cg);
        if (f_next < 0.99999f) {
            float rem = I / (1.0f - f_next);      // >= sum of future I
            if (rem * fmaxf(g, b * S) < 1e-4f) { fixed = true; break; }
        }
    }

    // tail (only if we never stopped early): run honestly to n
    if (!fixed) {
        while (t < n) {
            float f  = fmaf(b, S, cg);
            float t1 = b * I;
            float nS = fmaf(-t1, S, S);
            float nI = I * f;
            float nR = fmaf(g, I, R);
            S = nS; I = nI; R = nR;
            p[0] = S; p[1] = I; p[2] = R;
            p += 3;
            ++t;
        }
    }

    fi->t = t; fi->S = S; fi->I = I; fi->R = R;
}

// One float element per thread; elements >= 3*t0 get the frozen state.
__global__ void sir_fill(float* __restrict__ out, int total,
                         const FixInfo* __restrict__ fi) {
    int j = blockIdx.x * blockDim.x + threadIdx.x;
    if (j >= total) return;
    int j0 = 3 * fi->t;
    if (j < j0) return;
    int c = j % 3;
    float v = (c == 0) ? fi->S : (c == 1) ? fi->I : fi->R;
    out[j] = v;
}

extern "C" void kernel_launch(void* const* d_in, const int* in_sizes, int n_in,
                              void* d_out, int out_size, void* d_ws, size_t ws_size,
                              hipStream_t stream) {
    const float* x  = (const float*)d_in[0];
    const float* bw = (const float*)d_in[1];
    const float* gw = (const float*)d_in[2];
    float* out = (float*)d_out;
    int n = out_size / 3;  // steps - 1 rows

    FixInfo* fi = (FixInfo*)d_ws;

    sir_scan<<<1, 64, 0, stream>>>(x, bw, gw, out, n, fi);

    int blocks = (out_size + 255) / 256;
    sir_fill<<<blocks, 256, 0, stream>>>(out, out_size, fi);
}